// Round 4
// baseline (737.973 us; speedup 1.0000x reference)
//
#include <hip/hip_runtime.h>
#include <cstdint>
#include <cstddef>

// ---------------------------------------------------------------------------
// Sizes: C=512,H=4,W=4,SPLIT=4,WC=1 -> L=2048, B=16, gates=4*L=8192
// 8 weight matrices of [8192][2048] fp32 (enc/dec x ih/hh x layer0/1).
// Packed layout per matrix: 512 ch-tiles x 64 k-steps, each a 16x32 bf16
// fragment in MFMA lane order (lane l holds 8 bf16 at frag*512 + l*8).
// Fragment map: A-row r -> weight row (r>>2)*2048 + bt*4 + (r&3);
//               k = ks*32 + (l>>4)*8 + j.
// Activations use the same per-fragment packing with col = batch n.
// ---------------------------------------------------------------------------

typedef __attribute__((ext_vector_type(8))) short short8;   // 8 x bf16
typedef __attribute__((ext_vector_type(4))) short short4v;
typedef __attribute__((ext_vector_type(4))) float f32x4;

#define LD    2048
#define NBATCH 16
#define LAYER_W  16777216ull      // elems per [8192][2048] matrix

__device__ __forceinline__ short f2bf(float f) {
    union { float f; unsigned u; } c; c.f = f;
    unsigned u = c.u;
    unsigned r = (u + 0x7FFFu + ((u >> 16) & 1u)) >> 16;
    return (short)r;
}

__device__ __forceinline__ float sigmoidf_(float x) { return 1.f / (1.f + __expf(-x)); }

// packed offset for activation element (batch n, feature k)
__device__ __forceinline__ int apos(int n, int k) {
    return ((k >> 5) << 9) + ((((k >> 3) & 3) << 4) + n) * 8 + (k & 7);
}

// ---------------------------------------------------------------------------
// Pack all 8 matrices fp32 -> fragment-ordered bf16, via LDS staging.
// Grid 8192: block -> (om, bt, half); om 0..3 = dec (packed first), 4..7 enc.
// Phase 1: coalesced row-major read of [16][1024] fp32 tile -> bf16 LDS.
// Phase 2: linear fragment-order write (1KB contiguous per wave).
// ---------------------------------------------------------------------------
__global__ __launch_bounds__(256) void k_pack8(
    const float* __restrict__ enc_Wih, const float* __restrict__ enc_Whh,
    const float* __restrict__ dec_Wih, const float* __restrict__ dec_Whh,
    short* __restrict__ dstbase)
{
    __shared__ short lbuf[16 * 1032];   // padded rows: +8 shorts

    const int blk  = blockIdx.x;
    const int om   = blk >> 10;                 // 0..7, dec first
    const int mat  = (om < 4) ? (om + 4) : (om - 4);
    const int sub  = blk & 1023;
    const int bt   = sub >> 1;
    const int half = sub & 1;
    const int tid  = threadIdx.x;

    const float* srcs[4] = { enc_Wih, enc_Whh, dec_Wih, dec_Whh };
    const float* src = srcs[((mat >> 2) << 1) | ((mat >> 1) & 1)] + (size_t)(mat & 1) * LAYER_W;
    short* dst = dstbase + (size_t)mat * LAYER_W
               + (((size_t)bt * 64 + half * 32) << 9);

    // phase 1: 16 iters, 256 threads, f32x4 each
#pragma unroll 4
    for (int it = 0; it < 16; ++it) {
        int s = it * 256 + tid;                 // 0..4095
        int rl = s >> 8;                        // row-local 0..15
        int c0 = (s & 255) * 4;                 // col-local 0..1020
        int row = (rl >> 2) * 2048 + bt * 4 + (rl & 3);
        f32x4 v = __builtin_nontemporal_load(
            (const f32x4*)(src + (size_t)row * 2048 + half * 1024 + c0));
        short4v o;
        o[0] = f2bf(v[0]); o[1] = f2bf(v[1]); o[2] = f2bf(v[2]); o[3] = f2bf(v[3]);
        *(short4v*)(lbuf + rl * 1032 + c0) = o;
    }
    __syncthreads();

    // phase 2: 16 iters; output short idx = s*4 (fully linear)
#pragma unroll 4
    for (int it = 0; it < 16; ++it) {
        int s = it * 256 + tid;                 // 0..4095
        int fl   = s >> 7;                      // frag-local 0..31
        int w    = s & 127;
        int lane = w >> 1;
        int j0   = (s & 1) * 4;
        int rl   = lane & 15;
        int c0   = fl * 32 + (lane >> 4) * 8 + j0;
        short4v o = *(const short4v*)(lbuf + rl * 1032 + c0);
        *(short4v*)(dst + (size_t)s * 4) = o;
    }
}

// ---------------------------------------------------------------------------
// Init: zero h/c state + pack inputs + verbatim copies x1->out[1], x2->out[6]
// hbuf: [layer][parity][branch][32768] bf16 ; cst: [layer][branch][16][2048] f32
// ---------------------------------------------------------------------------
__global__ __launch_bounds__(256) void k_init(
    const float* __restrict__ x1, const float* __restrict__ x2,
    short* __restrict__ xc1, short* __restrict__ xc2,
    short* __restrict__ hbuf, float* __restrict__ cst,
    float* __restrict__ out)
{
    int i = blockIdx.x * blockDim.x + threadIdx.x;  // 131072 threads
    cst[i] = 0.f;
    if (i < 65536) { hbuf[i] = 0; hbuf[131072 + i] = 0; }
    if (i < 32768) {
        int b = i >> 11, l = i & 2047;
        f32x4 v1 = ((const f32x4*)x1)[i];   // x1[b, l, w=0..3]
        f32x4 v2 = ((const f32x4*)x2)[i];
        int p = apos(b, l);
#pragma unroll
        for (int s = 0; s < 4; ++s) {
            xc1[s * 32768 + p] = f2bf(v1[s]);
            xc2[s * 32768 + p] = f2bf(v2[s]);
        }
        ((f32x4*)(out + 131072))[i]     = v1;   // x1_parts[0] == x1
        ((f32x4*)(out + 6 * 131072))[i] = v2;   // x2_parts[2] == x2
    }
}

// ---------------------------------------------------------------------------
// LSTM cell, both branches. Dual-job: blocks [0,512) run jA, [512,1024) jB.
// Block owns 4 channels; 8 waves split K (4x Wih quarters, 4x Whh quarters).
// All hot-loop loads are 1KB-contiguous fragment streams.
// ---------------------------------------------------------------------------
struct CellJob {
    const short *Wih, *Whh;        // packed [512][64][512] bf16
    const float *bih, *bhh;        // [8192] fp32
    const short *xA, *xB, *hin;    // packed acts (hin: 2 branches x 32768)
    float *cst;                    // [2][16][2048] fp32 in-place
    short *hout;                   // packed [2][32768]
    float *svA, *svB;              // optional fp32 [16][2048]
};

__global__ __launch_bounds__(512, 4) void k_cell(CellJob jA, CellJob jB)
{
    __shared__ float gpart[8][2][16][17];

    const CellJob& J = (blockIdx.x < 512) ? jA : jB;
    const int bt   = blockIdx.x & 511;
    const int tid  = threadIdx.x;
    const int w    = tid >> 6;
    const int lane = tid & 63;
    const int r    = lane & 15;
    const int g4   = lane >> 4;
    const int kq   = w & 3;

    const short* Wsrc = (w < 4) ? J.Wih : J.Whh;
    const short* uA   = (w < 4) ? J.xA : J.hin;
    const short* uB   = (w < 4) ? J.xB : (J.hin + 32768);

    const short* wp = Wsrc + (((size_t)bt * 64 + kq * 16) << 9) + lane * 8;
    const short* ap = uA + ((kq * 16) << 9) + lane * 8;
    const short* bp = uB + ((kq * 16) << 9) + lane * 8;

    f32x4 accA = {0.f, 0.f, 0.f, 0.f};
    f32x4 accB = {0.f, 0.f, 0.f, 0.f};

#pragma unroll
    for (int half = 0; half < 2; ++half) {
        short8 wreg[8];
#pragma unroll
        for (int i = 0; i < 8; ++i)
            wreg[i] = *(const short8*)(wp + ((half * 8 + i) << 9));
#pragma unroll
        for (int i = 0; i < 8; ++i) {
            short8 av = *(const short8*)(ap + ((half * 8 + i) << 9));
            short8 bv = *(const short8*)(bp + ((half * 8 + i) << 9));
            accA = __builtin_amdgcn_mfma_f32_16x16x32_bf16(wreg[i], av, accA, 0, 0, 0);
            accB = __builtin_amdgcn_mfma_f32_16x16x32_bf16(wreg[i], bv, accB, 0, 0, 0);
        }
    }

    // C layout: col = lane&15, row m = g4*4+q  (m -> gate m>>2, chl m&3)
#pragma unroll
    for (int q = 0; q < 4; ++q) {
        gpart[w][0][g4 * 4 + q][r] = accA[q];
        gpart[w][1][g4 * 4 + q][r] = accB[q];
    }
    __syncthreads();

    if (tid < 128) {
        const int br  = tid >> 6;
        const int chl = (tid >> 4) & 3;
        const int n   = tid & 15;

        float gi = 0.f, gf = 0.f, gg = 0.f, go = 0.f;
#pragma unroll
        for (int ww = 0; ww < 8; ++ww) {
            gi += gpart[ww][br][chl][n];
            gf += gpart[ww][br][4 + chl][n];
            gg += gpart[ww][br][8 + chl][n];
            go += gpart[ww][br][12 + chl][n];
        }
        const int ch = bt * 4 + chl;
        gi += J.bih[ch]            + J.bhh[ch];
        gf += J.bih[2048 + ch]     + J.bhh[2048 + ch];
        gg += J.bih[2 * 2048 + ch] + J.bhh[2 * 2048 + ch];
        go += J.bih[3 * 2048 + ch] + J.bhh[3 * 2048 + ch];

        const size_t idx = ((size_t)br * NBATCH + n) * LD + ch;
        float cold = J.cst[idx];
        float cn = sigmoidf_(gf) * cold + sigmoidf_(gi) * tanhf(gg);
        float hn = sigmoidf_(go) * tanhf(cn);
        J.cst[idx] = cn;
        J.hout[br * 32768 + apos(n, ch)] = f2bf(hn);
        if (br == 0) { if (J.svA) J.svA[(size_t)n * LD + ch] = hn; }
        else         { if (J.svB) J.svB[(size_t)n * LD + ch] = hn; }
    }
}

// ---------------------------------------------------------------------------
// Finish: out[2..5] scatter + 1x1 conv + leaky relu -> out[0]
// blocks [0,1024): scatter; [1024,1280): conv
// ---------------------------------------------------------------------------
__global__ __launch_bounds__(512) void k_fin(
    const float* __restrict__ Wc, const float* __restrict__ bc,
    const float* __restrict__ SA, const float* __restrict__ SB,
    float* __restrict__ out)
{
    if (blockIdx.x < 1024) {
        int i = blockIdx.x * 512 + threadIdx.x;   // 4*131072
        int q  = i >> 17;
        int rr = i & 131071;
        int w  = rr & 3;
        int l  = (rr >> 2) & 2047;
        int b  = rr >> 13;
        const float* src;
        if (q == 0)      src = SA + (size_t)w       * 32768;
        else if (q == 1) src = SA + (size_t)(4 + w) * 32768;
        else if (q == 2) src = SB + (size_t)(7 - w) * 32768;
        else             src = SB + (size_t)(3 - w) * 32768;
        out[(size_t)(2 + q) * 131072 + rr] = src[(size_t)b * 2048 + l];
        return;
    }
    __shared__ float mid[1024];
    int blk = blockIdx.x - 1024;     // 0..255
    int b = blk >> 4, hw = blk & 15, h = hw >> 2, w = hw & 3;
    int o = threadIdx.x;             // 0..511
    mid[o]       = SA[(size_t)w       * 32768 + (size_t)b * 2048 + o * 4 + h];
    mid[o + 512] = SB[(size_t)(3 - w) * 32768 + (size_t)b * 2048 + o * 4 + h];
    __syncthreads();
    float acc = bc[o];
    const f32x4* wr = (const f32x4*)(Wc + (size_t)o * 1024);
#pragma unroll 4
    for (int i2 = 0; i2 < 256; ++i2) {
        f32x4 wv = wr[i2];
        acc += wv[0] * mid[i2 * 4] + wv[1] * mid[i2 * 4 + 1]
             + wv[2] * mid[i2 * 4 + 2] + wv[3] * mid[i2 * 4 + 3];
    }
    out[(size_t)b * 8192 + o * 16 + h * 4 + w] = acc > 0.f ? acc : 0.2f * acc;
}

__global__ void k_wsfail(float* out) { if (threadIdx.x == 0 && blockIdx.x == 0) out[0] = -7.7e7f; }

// ---------------------------------------------------------------------------
extern "C" void kernel_launch(void* const* d_in, const int* in_sizes, int n_in,
                              void* d_out, int out_size, void* d_ws, size_t ws_size,
                              hipStream_t stream)
{
    const float* x1      = (const float*)d_in[0];
    const float* x2      = (const float*)d_in[1];
    const float* enc_Wih = (const float*)d_in[2];
    const float* enc_Whh = (const float*)d_in[3];
    const float* enc_bih = (const float*)d_in[4];
    const float* enc_bhh = (const float*)d_in[5];
    const float* dec_Wih = (const float*)d_in[6];
    const float* dec_Whh = (const float*)d_in[7];
    const float* dec_bih = (const float*)d_in[8];
    const float* dec_bhh = (const float*)d_in[9];
    const float* conv_W  = (const float*)d_in[10];
    const float* conv_b  = (const float*)d_in[11];
    float* out = (float*)d_out;

    // workspace: 8 packed matrices (mat = (enc?0:4) + hh*2 + layer)
    short* Wb  = (short*)d_ws;                 // 8 * LAYER_W bf16
    short* xc1 = Wb + 8 * LAYER_W;             // 4 chunks * 32768
    short* xc2 = xc1 + 131072;
    short* hbuf = xc2 + 131072;                // [2][2][2][32768] bf16
    float* cst  = (float*)(hbuf + 262144);     // [2][2][16][2048] fp32
    float* SA   = cst + 131072;                // 8 slots * [16][2048] fp32
    float* SB   = SA + 262144;
    size_t need = (size_t)((char*)(SB + 262144) - (char*)d_ws);
    if (ws_size < need) { k_wsfail<<<1, 64, 0, stream>>>(out); return; }

    k_init<<<512, 256, 0, stream>>>(x1, x2, xc1, xc2, hbuf, cst, out);
    k_pack8<<<8192, 256, 0, stream>>>(enc_Wih, enc_Whh, dec_Wih, dec_Whh, Wb);

    auto hB = [&](int layer, int par) { return hbuf + layer * 131072 + par * 65536; };

    auto mkJob = [&](int t, int layer) -> CellJob {
        const bool enc = (t <= 4);
        CellJob j;
        int base = enc ? 0 : 4;
        j.Wih = Wb + (size_t)(base + layer) * LAYER_W;
        j.Whh = Wb + (size_t)(base + 2 + layer) * LAYER_W;
        j.bih = (enc ? enc_bih : dec_bih) + layer * 8192;
        j.bhh = (enc ? enc_bhh : dec_bhh) + layer * 8192;
        if (layer == 0) {
            if (t <= 4)      { j.xA = xc2 + (size_t)(t - 1) * 32768; j.xB = xc1 + (size_t)(4 - t) * 32768; }
            else if (t <= 8) { j.xA = xc1 + (size_t)(t - 5) * 32768; j.xB = xc2 + (size_t)(8 - t) * 32768; }
            else             { const short* hp = hB(1, (t - 1) & 1); j.xA = hp; j.xB = hp + 32768; }
            j.hin = hB(0, (t - 1) & 1);
            j.cst = cst;
            j.hout = hB(0, t & 1);
            j.svA = nullptr; j.svB = nullptr;
        } else {
            const short* hx = hB(0, t & 1);
            j.xA = hx; j.xB = hx + 32768;
            j.hin = hB(1, (t - 1) & 1);
            j.cst = cst + 65536;
            j.hout = hB(1, t & 1);
            j.svA = (t >= 8) ? SA + (size_t)(t - 8) * 32768 : nullptr;
            j.svB = (t >= 8) ? SB + (size_t)(t - 8) * 32768 : nullptr;
        }
        return j;
    };

    // t=1 layer0 alone
    k_cell<<<512, 512, 0, stream>>>(mkJob(1, 0), mkJob(1, 0));
    // t=2..8: layer0(t) || layer1(t-1)  (independent)
    for (int t = 2; t <= 8; ++t)
        k_cell<<<1024, 512, 0, stream>>>(mkJob(t, 0), mkJob(t - 1, 1));
    // layer1(8) alone
    k_cell<<<512, 512, 0, stream>>>(mkJob(8, 1), mkJob(8, 1));
    // AR steps: strictly serial
    for (int t = 9; t <= 15; ++t) {
        k_cell<<<512, 512, 0, stream>>>(mkJob(t, 0), mkJob(t, 0));
        k_cell<<<512, 512, 0, stream>>>(mkJob(t, 1), mkJob(t, 1));
    }

    k_fin<<<1280, 512, 0, stream>>>(conv_W, conv_b, SA, SB, out);
}

// Round 5
// 384.208 us; speedup vs baseline: 1.9208x; 1.9208x over previous
//
#include <hip/hip_runtime.h>
#include <cstdint>
#include <cstddef>

// ---------------------------------------------------------------------------
// Sizes: C=512,H=4,W=4,SPLIT=4,WC=1 -> L=2048, B=16, gates=4*L=8192
// 8 weight matrices of [8192][2048] fp32 -> fp8 e4m3 (x64 scale), packed as
// 512 ch-tiles x 64 k-steps, each a 16x32 fragment in MFMA lane order
// (lane l holds 8 bytes at frag*512 + l*8).
// Fragment map: A-row r -> weight row (r>>2)*2048 + bt*4 + (r&3);
//               k = ks*32 + (l>>4)*8 + j.
// Activations: same per-fragment packing (fp8, unscaled), col = batch n.
// Gate epilogue multiplies the MFMA sum by 1/64.
// ---------------------------------------------------------------------------

typedef __attribute__((ext_vector_type(8))) short short8;   // 8 x bf16
typedef __attribute__((ext_vector_type(4))) short short4v;
typedef __attribute__((ext_vector_type(4))) float f32x4;

#define NBATCH 16
#define MAT_B   16777216ull     // bytes per packed fp8 matrix (8192*2048)
#define WSCALE  64.0f
#define INVWS   (1.0f / 64.0f)

__device__ __forceinline__ short f2bf(float f) {
    union { float f; unsigned u; } c; c.f = f;
    unsigned u = c.u;
    unsigned r = (u + 0x7FFFu + ((u >> 16) & 1u)) >> 16;
    return (short)r;
}

// software OCP e4m3fn quantize, RNE, saturating (no inf; 0x7F=NaN avoided)
__device__ __forceinline__ uint32_t f2fp8(float x) {
    union { float f; uint32_t u; } v; v.f = x;
    uint32_t sgn = (v.u >> 24) & 0x80u;
    uint32_t au  = v.u & 0x7FFFFFFFu;
    if (au == 0u) return sgn;
    if (au >= 0x43E00000u) return sgn | 0x7Eu;        // >=448 -> sat to 448
    v.u = au;
    float af = v.f;
    int e = (int)(au >> 23) - 127;
    if (e < -6) {                                      // subnormal: m * 2^-9
        int mi = (int)rintf(af * 512.f);
        if (mi == 0) return sgn;
        if (mi < 8)  return sgn | (uint32_t)mi;
        return sgn | 0x08u;                            // rounded to min normal
    }
    int mi = (int)rintf(ldexpf(af, 3 - e));            // in [8,16]
    if (mi == 16) { ++e; mi = 8; }
    return sgn | ((uint32_t)(e + 7) << 3) | (uint32_t)(mi & 7);
}

__device__ __forceinline__ float sigmoidf_(float x) { return 1.f / (1.f + __expf(-x)); }

// packed byte offset for activation element (batch n, feature k)
__device__ __forceinline__ int apos(int n, int k) {
    return ((k >> 5) << 9) + ((((k >> 3) & 3) << 4) + n) * 8 + (k & 7);
}

// ---------------------------------------------------------------------------
// Pack all 8 matrices fp32 -> fragment-ordered fp8 (x64), via LDS staging.
// Grid 8192: block -> (om, bt, half); om 0..3 = dec (packed first), 4..7 enc.
// ---------------------------------------------------------------------------
__global__ __launch_bounds__(256) void k_pack8(
    const float* __restrict__ enc_Wih, const float* __restrict__ enc_Whh,
    const float* __restrict__ dec_Wih, const float* __restrict__ dec_Whh,
    uint8_t* __restrict__ dstbase)
{
    __shared__ uint8_t lbuf[16 * 1032];

    const int blk  = blockIdx.x;
    const int om   = blk >> 10;
    const int mat  = (om + 4) & 7;              // dec (4..7) first, enc (0..3) last
    const int sub  = blk & 1023;
    const int bt   = sub >> 1;
    const int half = sub & 1;
    const int tid  = threadIdx.x;

    const float* srcs[4] = { enc_Wih, enc_Whh, dec_Wih, dec_Whh };
    const float* src = srcs[mat >> 1] + (size_t)(mat & 1) * 16777216ull;
    uint8_t* dst = dstbase + (size_t)mat * MAT_B
                 + (((size_t)bt * 64 + half * 32) << 9);

    // phase 1: coalesced row reads -> fp8 LDS tile [16][1024] (+8 pad)
#pragma unroll 4
    for (int it = 0; it < 16; ++it) {
        int s  = it * 256 + tid;                // 0..4095
        int rl = s >> 8;
        int c0 = (s & 255) * 4;
        int row = (rl >> 2) * 2048 + bt * 4 + (rl & 3);
        f32x4 v = __builtin_nontemporal_load(
            (const f32x4*)(src + (size_t)row * 2048 + half * 1024 + c0));
        uint32_t w32 = f2fp8(v[0] * WSCALE) | (f2fp8(v[1] * WSCALE) << 8)
                     | (f2fp8(v[2] * WSCALE) << 16) | (f2fp8(v[3] * WSCALE) << 24);
        *(uint32_t*)(lbuf + rl * 1032 + c0) = w32;
    }
    __syncthreads();

    // phase 2: fragment-order linear writes (16 KB per block)
#pragma unroll 4
    for (int it = 0; it < 16; ++it) {
        int s    = it * 256 + tid;              // 0..4095, 4 bytes each
        int fl   = s >> 7;                      // frag-local 0..31
        int w    = s & 127;
        int lane = w >> 1;
        int j0   = (s & 1) * 4;
        int rl   = lane & 15;
        int c0   = fl * 32 + (lane >> 4) * 8 + j0;
        *(uint32_t*)(dst + (size_t)s * 4) = *(const uint32_t*)(lbuf + rl * 1032 + c0);
    }
}

// ---------------------------------------------------------------------------
// Pack conv weights [512][1024] fp32 -> bf16 fragments (32 mt-tiles)
// ---------------------------------------------------------------------------
__global__ __launch_bounds__(256) void k_packc(const float* __restrict__ Wc,
                                               short* __restrict__ Wcp)
{
    __shared__ short lb[16 * 1032];
    const int mt = blockIdx.x, tid = threadIdx.x;
#pragma unroll 4
    for (int it = 0; it < 16; ++it) {
        int s = it * 256 + tid;                 // 0..4095
        int rl = s >> 8;
        int c0 = (s & 255) * 4;
        f32x4 v = *(const f32x4*)(Wc + (size_t)(mt * 16 + rl) * 1024 + c0);
        short4v o;
        o[0] = f2bf(v[0]); o[1] = f2bf(v[1]); o[2] = f2bf(v[2]); o[3] = f2bf(v[3]);
        *(short4v*)(lb + rl * 1032 + c0) = o;
    }
    __syncthreads();
    short* dst = Wcp + (size_t)mt * 16384;
#pragma unroll 4
    for (int it = 0; it < 16; ++it) {
        int s    = it * 256 + tid;              // 4 shorts each
        int fl   = s >> 7;
        int w    = s & 127;
        int lane = w >> 1;
        int j0   = (s & 1) * 4;
        int rl   = lane & 15;
        int c0   = fl * 32 + (lane >> 4) * 8 + j0;
        *(short4v*)(dst + (size_t)s * 4) = *(const short4v*)(lb + rl * 1032 + c0);
    }
}

// ---------------------------------------------------------------------------
// Init: zero h/c + pack inputs (fp8) + verbatim copies x1->out[1], x2->out[6]
// ---------------------------------------------------------------------------
__global__ __launch_bounds__(256) void k_init(
    const float* __restrict__ x1, const float* __restrict__ x2,
    uint8_t* __restrict__ xc1, uint8_t* __restrict__ xc2,
    uint8_t* __restrict__ hbuf, float* __restrict__ cst,
    float* __restrict__ out)
{
    int i = blockIdx.x * blockDim.x + threadIdx.x;  // 131072 threads
    cst[i] = 0.f;
    if (i < 65536) { hbuf[i] = 0; hbuf[131072 + i] = 0; }
    if (i < 32768) {
        int b = i >> 11, l = i & 2047;
        f32x4 v1 = ((const f32x4*)x1)[i];
        f32x4 v2 = ((const f32x4*)x2)[i];
        int p = apos(b, l);
#pragma unroll
        for (int s = 0; s < 4; ++s) {
            xc1[s * 32768 + p] = (uint8_t)f2fp8(v1[s]);
            xc2[s * 32768 + p] = (uint8_t)f2fp8(v2[s]);
        }
        ((f32x4*)(out + 131072))[i]     = v1;   // x1_parts[0] == x1
        ((f32x4*)(out + 6 * 131072))[i] = v2;   // x2_parts[2] == x2
    }
}

// ---------------------------------------------------------------------------
// LSTM cell (fp8), both branches. Dual-job: blocks [0,512)=jA, [512,1024)=jB.
// Block owns 4 channels; 8 waves split K (4x Wih quarters, 4x Whh quarters).
// ---------------------------------------------------------------------------
struct CellJob {
    const uint8_t *Wih, *Whh;      // packed fp8 [512][64][512B]
    const float *bih, *bhh;        // [8192] fp32
    const uint8_t *xA, *xB, *hin;  // packed fp8 acts (hin: 2 branches x 32768B)
    float *cst;                    // [2][16][2048] fp32 in-place
    uint8_t *hout;                 // packed fp8 [2][32768]
    float *svA, *svB;              // optional fp32 [16][2048]
    short *midp;                   // optional bf16 conv-B fragments
    int slot;
};

__global__ __launch_bounds__(512, 4) void k_cell(CellJob jA, CellJob jB)
{
    __shared__ float gpart[8][2][16][17];

    const CellJob& J = (blockIdx.x < 512) ? jA : jB;
    const int bt   = blockIdx.x & 511;
    const int tid  = threadIdx.x;
    const int w    = tid >> 6;
    const int lane = tid & 63;
    const int r    = lane & 15;
    const int g4   = lane >> 4;
    const int kq   = w & 3;

    const uint8_t* Wsrc = (w < 4) ? J.Wih : J.Whh;
    const uint8_t* uA   = (w < 4) ? J.xA : J.hin;
    const uint8_t* uB   = (w < 4) ? J.xB : (J.hin + 32768);

    const uint8_t* wp = Wsrc + (((size_t)bt * 64 + kq * 16) << 9) + lane * 8;
    const uint8_t* ap = uA + ((kq * 16) << 9) + lane * 8;
    const uint8_t* bp = uB + ((kq * 16) << 9) + lane * 8;

    long wreg[16];
#pragma unroll
    for (int i = 0; i < 16; ++i)
        wreg[i] = *(const long*)(wp + ((size_t)i << 9));

    f32x4 accA = {0.f, 0.f, 0.f, 0.f};
    f32x4 accB = {0.f, 0.f, 0.f, 0.f};
#pragma unroll
    for (int i = 0; i < 16; ++i) {
        long av = *(const long*)(ap + ((size_t)i << 9));
        long bv = *(const long*)(bp + ((size_t)i << 9));
        accA = __builtin_amdgcn_mfma_f32_16x16x32_fp8_fp8(wreg[i], av, accA, 0, 0, 0);
        accB = __builtin_amdgcn_mfma_f32_16x16x32_fp8_fp8(wreg[i], bv, accB, 0, 0, 0);
    }

    // C layout: col = lane&15, row m = g4*4+q  (m -> gate m>>2, chl m&3)
#pragma unroll
    for (int q = 0; q < 4; ++q) {
        gpart[w][0][g4 * 4 + q][r] = accA[q];
        gpart[w][1][g4 * 4 + q][r] = accB[q];
    }
    __syncthreads();

    if (tid < 128) {
        const int br  = tid >> 6;
        const int chl = (tid >> 4) & 3;
        const int n   = tid & 15;

        float gi = 0.f, gf = 0.f, gg = 0.f, go = 0.f;
#pragma unroll
        for (int ww = 0; ww < 8; ++ww) {
            gi += gpart[ww][br][chl][n];
            gf += gpart[ww][br][4 + chl][n];
            gg += gpart[ww][br][8 + chl][n];
            go += gpart[ww][br][12 + chl][n];
        }
        const int ch = bt * 4 + chl;
        gi = gi * INVWS + J.bih[ch]            + J.bhh[ch];
        gf = gf * INVWS + J.bih[2048 + ch]     + J.bhh[2048 + ch];
        gg = gg * INVWS + J.bih[2 * 2048 + ch] + J.bhh[2 * 2048 + ch];
        go = go * INVWS + J.bih[3 * 2048 + ch] + J.bhh[3 * 2048 + ch];

        const size_t idx = ((size_t)br * NBATCH + n) * 2048 + ch;
        float cold = J.cst[idx];
        float cn = sigmoidf_(gf) * cold + sigmoidf_(gi) * tanhf(gg);
        float hn = sigmoidf_(go) * tanhf(cn);
        J.cst[idx] = cn;
        J.hout[br * 32768 + apos(n, ch)] = (uint8_t)f2fp8(hn);
        if (br == 0) { if (J.svA) J.svA[(size_t)n * 2048 + ch] = hn; }
        else         { if (J.svB) J.svB[(size_t)n * 2048 + ch] = hn; }
        if (J.midp) {
            int i8, pos;
            if (br == 0) { i8 = ch >> 2;       pos = n * 16 + (ch & 3) * 4 + J.slot; }
            else         { i8 = 512 + (ch >> 2); pos = n * 16 + (ch & 3) * 4 + (3 - J.slot); }
            J.midp[(pos >> 4) * 16384 + (i8 >> 5) * 512
                   + (((i8 >> 3) & 3) * 16 + (pos & 15)) * 8 + (i8 & 7)] = f2bf(hn);
        }
    }
}

// ---------------------------------------------------------------------------
// out[2..5] scatter, coalesced both sides. thread = (q, b, l); f32x4 write.
// out2=[de1,p1,p2,p3]=SA[w]; out3=SA[4+w]; out4=SB[7-w]; out5=SB[3-w]
// ---------------------------------------------------------------------------
__global__ __launch_bounds__(512) void k_outs(const float* __restrict__ SA,
                                              const float* __restrict__ SB,
                                              float* __restrict__ out)
{
    int i  = blockIdx.x * 512 + threadIdx.x;   // 0..131071
    int q  = i >> 15;
    int rr = i & 32767;
    const float* base = (q < 2) ? SA : SB;
    int sl0 = (q == 0) ? 0 : (q == 1) ? 4 : (q == 2) ? 7 : 3;
    int stp = (q < 2) ? 1 : -1;
    f32x4 o;
#pragma unroll
    for (int w2 = 0; w2 < 4; ++w2)
        o[w2] = base[(size_t)(sl0 + stp * w2) * 32768 + rr];
    ((f32x4*)(out + (size_t)(2 + q) * 131072))[rr] = o;
}

// ---------------------------------------------------------------------------
// 1x1 conv as packed MFMA GEMM: out0[512 x 256pos] = Wcp[512][1024] x midp
// grid 512 = (mt 0..31) x (nt 0..15); 4 waves split K=1024.
// ---------------------------------------------------------------------------
__global__ __launch_bounds__(256) void k_conv2(const short* __restrict__ Wcp,
                                               const short* __restrict__ midp,
                                               const float* __restrict__ bc,
                                               float* __restrict__ out)
{
    __shared__ float gp[4][16][17];
    const int mt = blockIdx.x >> 4, nt = blockIdx.x & 15;
    const int tid = threadIdx.x, kw = tid >> 6, lane = tid & 63;
    const short* ap = Wcp + (size_t)mt * 16384 + kw * 8 * 512 + lane * 8;
    const short* bp = midp + (size_t)nt * 16384 + kw * 8 * 512 + lane * 8;
    f32x4 acc = {0.f, 0.f, 0.f, 0.f};
#pragma unroll
    for (int i = 0; i < 8; ++i) {
        short8 a = *(const short8*)(ap + i * 512);
        short8 b = *(const short8*)(bp + i * 512);
        acc = __builtin_amdgcn_mfma_f32_16x16x32_bf16(a, b, acc, 0, 0, 0);
    }
    const int r = lane & 15, g4 = lane >> 4;
#pragma unroll
    for (int q = 0; q < 4; ++q) gp[kw][g4 * 4 + q][r] = acc[q];
    __syncthreads();

    const int m = tid >> 4, nl = tid & 15;
    float s = gp[0][m][nl] + gp[1][m][nl] + gp[2][m][nl] + gp[3][m][nl];
    const int o = mt * 16 + m, pos = nt * 16 + nl;
    s += bc[o];
    s = s > 0.f ? s : 0.2f * s;
    const int b = pos >> 4, hp = (pos >> 2) & 3, w = pos & 3;
    out[(size_t)b * 8192 + o * 16 + hp * 4 + w] = s;
}

__global__ void k_wsfail(float* out) { if (threadIdx.x == 0 && blockIdx.x == 0) out[0] = -7.7e7f; }

// ---------------------------------------------------------------------------
extern "C" void kernel_launch(void* const* d_in, const int* in_sizes, int n_in,
                              void* d_out, int out_size, void* d_ws, size_t ws_size,
                              hipStream_t stream)
{
    const float* x1      = (const float*)d_in[0];
    const float* x2      = (const float*)d_in[1];
    const float* enc_Wih = (const float*)d_in[2];
    const float* enc_Whh = (const float*)d_in[3];
    const float* enc_bih = (const float*)d_in[4];
    const float* enc_bhh = (const float*)d_in[5];
    const float* dec_Wih = (const float*)d_in[6];
    const float* dec_Whh = (const float*)d_in[7];
    const float* dec_bih = (const float*)d_in[8];
    const float* dec_bhh = (const float*)d_in[9];
    const float* conv_W  = (const float*)d_in[10];
    const float* conv_b  = (const float*)d_in[11];
    float* out = (float*)d_out;

    // workspace (mats 0..3 = enc{ihL0,ihL1,hhL0,hhL1}, 4..7 = dec)
    uint8_t* Wb   = (uint8_t*)d_ws;            // 8 * MAT_B fp8
    uint8_t* xc1  = Wb + 8 * MAT_B;            // 4 chunks * 32768 B
    uint8_t* xc2  = xc1 + 131072;
    uint8_t* hbuf = xc2 + 131072;              // [2][2][2][32768] fp8
    float*   cst  = (float*)(hbuf + 262144);   // [2][2][16][2048] fp32
    float*   SA   = cst + 131072;              // 8 slots * 32768 fp32
    float*   SB   = SA + 262144;
    short*   midp = (short*)(SB + 262144);     // 16 nt * 16384 bf16
    short*   Wcp  = midp + 262144;             // 32 mt * 16384 bf16
    size_t need = (size_t)((char*)(Wcp + 524288) - (char*)d_ws);
    if (ws_size < need) { k_wsfail<<<1, 64, 0, stream>>>(out); return; }

    k_init<<<512, 256, 0, stream>>>(x1, x2, xc1, xc2, hbuf, cst, out);
    k_pack8<<<8192, 256, 0, stream>>>(enc_Wih, enc_Whh, dec_Wih, dec_Whh, Wb);
    k_packc<<<32, 256, 0, stream>>>(conv_W, Wcp);

    auto hB = [&](int layer, int par) -> uint8_t* {
        return hbuf + layer * 131072 + par * 65536;
    };

    auto mkJob = [&](int t, int layer) -> CellJob {
        const bool enc = (t <= 4);
        CellJob j;
        int base = enc ? 0 : 4;
        j.Wih = Wb + (size_t)(base + layer) * MAT_B;
        j.Whh = Wb + (size_t)(base + 2 + layer) * MAT_B;
        j.bih = (enc ? enc_bih : dec_bih) + layer * 8192;
        j.bhh = (enc ? enc_bhh : dec_bhh) + layer * 8192;
        if (layer == 0) {
            if (t <= 4)      { j.xA = xc2 + (size_t)(t - 1) * 32768; j.xB = xc1 + (size_t)(4 - t) * 32768; }
            else if (t <= 8) { j.xA = xc1 + (size_t)(t - 5) * 32768; j.xB = xc2 + (size_t)(8 - t) * 32768; }
            else             { const uint8_t* hp = hB(1, (t - 1) & 1); j.xA = hp; j.xB = hp + 32768; }
            j.hin = hB(0, (t - 1) & 1);
            j.cst = cst;
            j.hout = hB(0, t & 1);
            j.svA = nullptr; j.svB = nullptr; j.midp = nullptr; j.slot = 0;
        } else {
            const uint8_t* hx = hB(0, t & 1);
            j.xA = hx; j.xB = hx + 32768;
            j.hin = hB(1, (t - 1) & 1);
            j.cst = cst + 65536;
            j.hout = hB(1, t & 1);
            j.svA = (t >= 8) ? SA + (size_t)(t - 8) * 32768 : nullptr;
            j.svB = (t >= 8) ? SB + (size_t)(t - 8) * 32768 : nullptr;
            j.midp = (t >= 8 && t <= 11) ? midp : nullptr;
            j.slot = (t >= 8) ? (t - 8) : 0;
        }
        return j;
    };

    // t=1 layer0 alone
    k_cell<<<512, 512, 0, stream>>>(mkJob(1, 0), mkJob(1, 0));
    // t=2..8: layer0(t) || layer1(t-1)  (independent)
    for (int t = 2; t <= 8; ++t)
        k_cell<<<1024, 512, 0, stream>>>(mkJob(t, 0), mkJob(t - 1, 1));
    // layer1(8) alone
    k_cell<<<512, 512, 0, stream>>>(mkJob(8, 1), mkJob(8, 1));
    // AR steps: strictly serial
    for (int t = 9; t <= 15; ++t) {
        k_cell<<<512, 512, 0, stream>>>(mkJob(t, 0), mkJob(t, 0));
        k_cell<<<512, 512, 0, stream>>>(mkJob(t, 1), mkJob(t, 1));
    }

    k_outs<<<256, 512, 0, stream>>>(SA, SB, out);
    k_conv2<<<512, 256, 0, stream>>>(Wcp, midp, conv_b, out);
}

// Round 6
// 377.243 us; speedup vs baseline: 1.9562x; 1.0185x over previous
//
#include <hip/hip_runtime.h>
#include <cstdint>
#include <cstddef>

// ---------------------------------------------------------------------------
// Sizes: C=512,H=4,W=4,SPLIT=4,WC=1 -> L=2048, B=16, gates=4*L=8192
// 8 weight matrices of [8192][2048] fp32 -> fp8 e4m3 (x64 scale), packed as
// 512 ch-tiles x 64 k-steps, each a 16x32 fragment in MFMA lane order
// (lane l holds 8 bytes at frag*512 + l*8).
// Fragment map: A-row r -> weight row (r>>2)*2048 + bt*4 + (r&3);
//               k = ks*32 + (l>>4)*8 + j.
// Activations: same per-fragment packing (fp8, unscaled), col = batch n.
// Gate epilogue multiplies the MFMA sum by 1/64.
// fp8 quantize uses HW v_cvt_pk_fp8_f32 (OCP e4m3fn on gfx950, RNE+sat).
// ---------------------------------------------------------------------------

typedef __attribute__((ext_vector_type(8))) short short8;   // 8 x bf16
typedef __attribute__((ext_vector_type(4))) short short4v;
typedef __attribute__((ext_vector_type(4))) float f32x4;

#define NBATCH 16
#define MAT_B   16777216ull     // bytes per packed fp8 matrix (8192*2048)
#define WSCALE  64.0f
#define INVWS   (1.0f / 64.0f)

__device__ __forceinline__ short f2bf(float f) {
    union { float f; unsigned u; } c; c.f = f;
    unsigned u = c.u;
    unsigned r = (u + 0x7FFFu + ((u >> 16) & 1u)) >> 16;
    return (short)r;
}

// HW packed fp8 quantize: 4 floats -> 4 OCP e4m3fn bytes (one dword)
__device__ __forceinline__ uint32_t f4_to_fp8x4(float a, float b, float c, float d) {
    int p = __builtin_amdgcn_cvt_pk_fp8_f32(a, b, 0, false);   // bytes 0,1
    p = __builtin_amdgcn_cvt_pk_fp8_f32(c, d, p, true);        // bytes 2,3
    return (uint32_t)p;
}

__device__ __forceinline__ uint8_t f2fp8hw(float x) {
    return (uint8_t)(__builtin_amdgcn_cvt_pk_fp8_f32(x, x, 0, false) & 0xFF);
}

__device__ __forceinline__ float sigmoidf_(float x) { return 1.f / (1.f + __expf(-x)); }

// packed byte offset for activation element (batch n, feature k)
__device__ __forceinline__ int apos(int n, int k) {
    return ((k >> 5) << 9) + ((((k >> 3) & 3) << 4) + n) * 8 + (k & 7);
}

// ---------------------------------------------------------------------------
// Pack all 8 matrices fp32 -> fragment-ordered fp8 (x64), via LDS staging.
// Grid 8192: block -> (om, bt, half); om 0..3 = dec (packed first), 4..7 enc.
// ---------------------------------------------------------------------------
__global__ __launch_bounds__(256) void k_pack8(
    const float* __restrict__ enc_Wih, const float* __restrict__ enc_Whh,
    const float* __restrict__ dec_Wih, const float* __restrict__ dec_Whh,
    uint8_t* __restrict__ dstbase)
{
    __shared__ uint8_t lbuf[16 * 1032];

    const int blk  = blockIdx.x;
    const int om   = blk >> 10;
    const int mat  = (om + 4) & 7;              // dec (4..7) first, enc (0..3) last
    const int sub  = blk & 1023;
    const int bt   = sub >> 1;
    const int half = sub & 1;
    const int tid  = threadIdx.x;

    const float* srcs[4] = { enc_Wih, enc_Whh, dec_Wih, dec_Whh };
    const float* src = srcs[mat >> 1] + (size_t)(mat & 1) * 16777216ull;
    uint8_t* dst = dstbase + (size_t)mat * MAT_B
                 + (((size_t)bt * 64 + half * 32) << 9);

    // phase 1: coalesced row reads -> fp8 LDS tile [16][1024] (+8 pad)
#pragma unroll 4
    for (int it = 0; it < 16; ++it) {
        int s  = it * 256 + tid;                // 0..4095
        int rl = s >> 8;
        int c0 = (s & 255) * 4;
        int row = (rl >> 2) * 2048 + bt * 4 + (rl & 3);
        f32x4 v = __builtin_nontemporal_load(
            (const f32x4*)(src + (size_t)row * 2048 + half * 1024 + c0));
        uint32_t w32 = f4_to_fp8x4(v[0] * WSCALE, v[1] * WSCALE,
                                   v[2] * WSCALE, v[3] * WSCALE);
        *(uint32_t*)(lbuf + rl * 1032 + c0) = w32;
    }
    __syncthreads();

    // phase 2: fragment-order linear writes (16 KB per block)
#pragma unroll 4
    for (int it = 0; it < 16; ++it) {
        int s    = it * 256 + tid;              // 0..4095, 4 bytes each
        int fl   = s >> 7;                      // frag-local 0..31
        int w    = s & 127;
        int lane = w >> 1;
        int j0   = (s & 1) * 4;
        int rl   = lane & 15;
        int c0   = fl * 32 + (lane >> 4) * 8 + j0;
        *(uint32_t*)(dst + (size_t)s * 4) = *(const uint32_t*)(lbuf + rl * 1032 + c0);
    }
}

// ---------------------------------------------------------------------------
// Pack conv weights [512][1024] fp32 -> bf16 fragments (32 mt-tiles)
// ---------------------------------------------------------------------------
__global__ __launch_bounds__(256) void k_packc(const float* __restrict__ Wc,
                                               short* __restrict__ Wcp)
{
    __shared__ short lb[16 * 1032];
    const int mt = blockIdx.x, tid = threadIdx.x;
#pragma unroll 4
    for (int it = 0; it < 16; ++it) {
        int s = it * 256 + tid;                 // 0..4095
        int rl = s >> 8;
        int c0 = (s & 255) * 4;
        f32x4 v = *(const f32x4*)(Wc + (size_t)(mt * 16 + rl) * 1024 + c0);
        short4v o;
        o[0] = f2bf(v[0]); o[1] = f2bf(v[1]); o[2] = f2bf(v[2]); o[3] = f2bf(v[3]);
        *(short4v*)(lb + rl * 1032 + c0) = o;
    }
    __syncthreads();
    short* dst = Wcp + (size_t)mt * 16384;
#pragma unroll 4
    for (int it = 0; it < 16; ++it) {
        int s    = it * 256 + tid;              // 4 shorts each
        int fl   = s >> 7;
        int w    = s & 127;
        int lane = w >> 1;
        int j0   = (s & 1) * 4;
        int rl   = lane & 15;
        int c0   = fl * 32 + (lane >> 4) * 8 + j0;
        *(short4v*)(dst + (size_t)s * 4) = *(const short4v*)(lb + rl * 1032 + c0);
    }
}

// ---------------------------------------------------------------------------
// Init: zero h/c + pack inputs (fp8) + verbatim copies x1->out[1], x2->out[6]
// ---------------------------------------------------------------------------
__global__ __launch_bounds__(256) void k_init(
    const float* __restrict__ x1, const float* __restrict__ x2,
    uint8_t* __restrict__ xc1, uint8_t* __restrict__ xc2,
    uint8_t* __restrict__ hbuf, float* __restrict__ cst,
    float* __restrict__ out)
{
    int i = blockIdx.x * blockDim.x + threadIdx.x;  // 131072 threads
    cst[i] = 0.f;
    if (i < 65536) { hbuf[i] = 0; hbuf[131072 + i] = 0; }
    if (i < 32768) {
        int b = i >> 11, l = i & 2047;
        f32x4 v1 = ((const f32x4*)x1)[i];
        f32x4 v2 = ((const f32x4*)x2)[i];
        int p = apos(b, l);
        uint32_t q1 = f4_to_fp8x4(v1[0], v1[1], v1[2], v1[3]);
        uint32_t q2 = f4_to_fp8x4(v2[0], v2[1], v2[2], v2[3]);
#pragma unroll
        for (int s = 0; s < 4; ++s) {
            xc1[s * 32768 + p] = (uint8_t)(q1 >> (8 * s));
            xc2[s * 32768 + p] = (uint8_t)(q2 >> (8 * s));
        }
        ((f32x4*)(out + 131072))[i]     = v1;   // x1_parts[0] == x1
        ((f32x4*)(out + 6 * 131072))[i] = v2;   // x2_parts[2] == x2
    }
}

// ---------------------------------------------------------------------------
// LSTM cell (fp8), both branches. Dual-job: blocks [0,512)=jA, [512,1024)=jB.
// Block owns 4 channels; 8 waves split K (4x Wih quarters, 4x Whh quarters).
// ---------------------------------------------------------------------------
struct CellJob {
    const uint8_t *Wih, *Whh;      // packed fp8 [512][64][512B]
    const float *bih, *bhh;        // [8192] fp32
    const uint8_t *xA, *xB, *hin;  // packed fp8 acts (hin: 2 branches x 32768B)
    float *cst;                    // [2][16][2048] fp32 in-place
    uint8_t *hout;                 // packed fp8 [2][32768]
    float *svA, *svB;              // optional fp32 [16][2048]
    short *midp;                   // optional bf16 conv-B fragments
    int slot;
};

__global__ __launch_bounds__(512, 4) void k_cell(CellJob jA, CellJob jB)
{
    __shared__ float gpart[8][2][16][17];

    const CellJob& J = (blockIdx.x < 512) ? jA : jB;
    const int bt   = blockIdx.x & 511;
    const int tid  = threadIdx.x;
    const int w    = tid >> 6;
    const int lane = tid & 63;
    const int r    = lane & 15;
    const int g4   = lane >> 4;
    const int kq   = w & 3;

    const uint8_t* Wsrc = (w < 4) ? J.Wih : J.Whh;
    const uint8_t* uA   = (w < 4) ? J.xA : J.hin;
    const uint8_t* uB   = (w < 4) ? J.xB : (J.hin + 32768);

    const uint8_t* wp = Wsrc + (((size_t)bt * 64 + kq * 16) << 9) + lane * 8;
    const uint8_t* ap = uA + ((kq * 16) << 9) + lane * 8;
    const uint8_t* bp = uB + ((kq * 16) << 9) + lane * 8;

    long wreg[16];
#pragma unroll
    for (int i = 0; i < 16; ++i)
        wreg[i] = *(const long*)(wp + ((size_t)i << 9));

    f32x4 accA = {0.f, 0.f, 0.f, 0.f};
    f32x4 accB = {0.f, 0.f, 0.f, 0.f};
#pragma unroll
    for (int i = 0; i < 16; ++i) {
        long av = *(const long*)(ap + ((size_t)i << 9));
        long bv = *(const long*)(bp + ((size_t)i << 9));
        accA = __builtin_amdgcn_mfma_f32_16x16x32_fp8_fp8(wreg[i], av, accA, 0, 0, 0);
        accB = __builtin_amdgcn_mfma_f32_16x16x32_fp8_fp8(wreg[i], bv, accB, 0, 0, 0);
    }

    // C layout: col = lane&15, row m = g4*4+q  (m -> gate m>>2, chl m&3)
#pragma unroll
    for (int q = 0; q < 4; ++q) {
        gpart[w][0][g4 * 4 + q][r] = accA[q];
        gpart[w][1][g4 * 4 + q][r] = accB[q];
    }
    __syncthreads();

    if (tid < 128) {
        const int br  = tid >> 6;
        const int chl = (tid >> 4) & 3;
        const int n   = tid & 15;

        float gi = 0.f, gf = 0.f, gg = 0.f, go = 0.f;
#pragma unroll
        for (int ww = 0; ww < 8; ++ww) {
            gi += gpart[ww][br][chl][n];
            gf += gpart[ww][br][4 + chl][n];
            gg += gpart[ww][br][8 + chl][n];
            go += gpart[ww][br][12 + chl][n];
        }
        const int ch = bt * 4 + chl;
        gi = gi * INVWS + J.bih[ch]            + J.bhh[ch];
        gf = gf * INVWS + J.bih[2048 + ch]     + J.bhh[2048 + ch];
        gg = gg * INVWS + J.bih[2 * 2048 + ch] + J.bhh[2 * 2048 + ch];
        go = go * INVWS + J.bih[3 * 2048 + ch] + J.bhh[3 * 2048 + ch];

        const size_t idx = ((size_t)br * NBATCH + n) * 2048 + ch;
        float cold = J.cst[idx];
        float cn = sigmoidf_(gf) * cold + sigmoidf_(gi) * tanhf(gg);
        float hn = sigmoidf_(go) * tanhf(cn);
        J.cst[idx] = cn;
        J.hout[br * 32768 + apos(n, ch)] = f2fp8hw(hn);
        if (br == 0) { if (J.svA) J.svA[(size_t)n * 2048 + ch] = hn; }
        else         { if (J.svB) J.svB[(size_t)n * 2048 + ch] = hn; }
        if (J.midp) {
            int i8, pos;
            if (br == 0) { i8 = ch >> 2;       pos = n * 16 + (ch & 3) * 4 + J.slot; }
            else         { i8 = 512 + (ch >> 2); pos = n * 16 + (ch & 3) * 4 + (3 - J.slot); }
            J.midp[(pos >> 4) * 16384 + (i8 >> 5) * 512
                   + (((i8 >> 3) & 3) * 16 + (pos & 15)) * 8 + (i8 & 7)] = f2bf(hn);
        }
    }
}

// ---------------------------------------------------------------------------
// out[2..5] scatter, coalesced both sides. thread = (q, b, l); f32x4 write.
// out2=[de1,p1,p2,p3]=SA[w]; out3=SA[4+w]; out4=SB[7-w]; out5=SB[3-w]
// ---------------------------------------------------------------------------
__global__ __launch_bounds__(512) void k_outs(const float* __restrict__ SA,
                                              const float* __restrict__ SB,
                                              float* __restrict__ out)
{
    int i  = blockIdx.x * 512 + threadIdx.x;   // 0..131071
    int q  = i >> 15;
    int rr = i & 32767;
    const float* base = (q < 2) ? SA : SB;
    int sl0 = (q == 0) ? 0 : (q == 1) ? 4 : (q == 2) ? 7 : 3;
    int stp = (q < 2) ? 1 : -1;
    f32x4 o;
#pragma unroll
    for (int w2 = 0; w2 < 4; ++w2)
        o[w2] = base[(size_t)(sl0 + stp * w2) * 32768 + rr];
    ((f32x4*)(out + (size_t)(2 + q) * 131072))[rr] = o;
}

// ---------------------------------------------------------------------------
// 1x1 conv as packed MFMA GEMM: out0[512 x 256pos] = Wcp[512][1024] x midp
// grid 512 = (mt 0..31) x (nt 0..15); 4 waves split K=1024.
// ---------------------------------------------------------------------------
__global__ __launch_bounds__(256) void k_conv2(const short* __restrict__ Wcp,
                                               const short* __restrict__ midp,
                                               const float* __restrict__ bc,
                                               float* __restrict__ out)
{
    __shared__ float gp[4][16][17];
    const int mt = blockIdx.x >> 4, nt = blockIdx.x & 15;
    const int tid = threadIdx.x, kw = tid >> 6, lane = tid & 63;
    const short* ap = Wcp + (size_t)mt * 16384 + kw * 8 * 512 + lane * 8;
    const short* bp = midp + (size_t)nt * 16384 + kw * 8 * 512 + lane * 8;
    f32x4 acc = {0.f, 0.f, 0.f, 0.f};
#pragma unroll
    for (int i = 0; i < 8; ++i) {
        short8 a = *(const short8*)(ap + i * 512);
        short8 b = *(const short8*)(bp + i * 512);
        acc = __builtin_amdgcn_mfma_f32_16x16x32_bf16(a, b, acc, 0, 0, 0);
    }
    const int r = lane & 15, g4 = lane >> 4;
#pragma unroll
    for (int q = 0; q < 4; ++q) gp[kw][g4 * 4 + q][r] = acc[q];
    __syncthreads();

    const int m = tid >> 4, nl = tid & 15;
    float s = gp[0][m][nl] + gp[1][m][nl] + gp[2][m][nl] + gp[3][m][nl];
    const int o = mt * 16 + m, pos = nt * 16 + nl;
    s += bc[o];
    s = s > 0.f ? s : 0.2f * s;
    const int b = pos >> 4, hp = (pos >> 2) & 3, w = pos & 3;
    out[(size_t)b * 8192 + o * 16 + hp * 4 + w] = s;
}

__global__ void k_wsfail(float* out) { if (threadIdx.x == 0 && blockIdx.x == 0) out[0] = -7.7e7f; }

// ---------------------------------------------------------------------------
extern "C" void kernel_launch(void* const* d_in, const int* in_sizes, int n_in,
                              void* d_out, int out_size, void* d_ws, size_t ws_size,
                              hipStream_t stream)
{
    const float* x1      = (const float*)d_in[0];
    const float* x2      = (const float*)d_in[1];
    const float* enc_Wih = (const float*)d_in[2];
    const float* enc_Whh = (const float*)d_in[3];
    const float* enc_bih = (const float*)d_in[4];
    const float* enc_bhh = (const float*)d_in[5];
    const float* dec_Wih = (const float*)d_in[6];
    const float* dec_Whh = (const float*)d_in[7];
    const float* dec_bih = (const float*)d_in[8];
    const float* dec_bhh = (const float*)d_in[9];
    const float* conv_W  = (const float*)d_in[10];
    const float* conv_b  = (const float*)d_in[11];
    float* out = (float*)d_out;

    // workspace (mats 0..3 = enc{ihL0,ihL1,hhL0,hhL1}, 4..7 = dec)
    uint8_t* Wb   = (uint8_t*)d_ws;            // 8 * MAT_B fp8
    uint8_t* xc1  = Wb + 8 * MAT_B;            // 4 chunks * 32768 B
    uint8_t* xc2  = xc1 + 131072;
    uint8_t* hbuf = xc2 + 131072;              // [2][2][2][32768] fp8
    float*   cst  = (float*)(hbuf + 262144);   // [2][2][16][2048] fp32
    float*   SA   = cst + 131072;              // 8 slots * 32768 fp32
    float*   SB   = SA + 262144;
    short*   midp = (short*)(SB + 262144);     // 16 nt * 16384 bf16
    short*   Wcp  = midp + 262144;             // 32 mt * 16384 bf16
    size_t need = (size_t)((char*)(Wcp + 524288) - (char*)d_ws);
    if (ws_size < need) { k_wsfail<<<1, 64, 0, stream>>>(out); return; }

    k_init<<<512, 256, 0, stream>>>(x1, x2, xc1, xc2, hbuf, cst, out);
    k_pack8<<<8192, 256, 0, stream>>>(enc_Wih, enc_Whh, dec_Wih, dec_Whh, Wb);
    k_packc<<<32, 256, 0, stream>>>(conv_W, Wcp);

    auto hB = [&](int layer, int par) -> uint8_t* {
        return hbuf + layer * 131072 + par * 65536;
    };

    auto mkJob = [&](int t, int layer) -> CellJob {
        const bool enc = (t <= 4);
        CellJob j;
        int base = enc ? 0 : 4;
        j.Wih = Wb + (size_t)(base + layer) * MAT_B;
        j.Whh = Wb + (size_t)(base + 2 + layer) * MAT_B;
        j.bih = (enc ? enc_bih : dec_bih) + layer * 8192;
        j.bhh = (enc ? enc_bhh : dec_bhh) + layer * 8192;
        if (layer == 0) {
            if (t <= 4)      { j.xA = xc2 + (size_t)(t - 1) * 32768; j.xB = xc1 + (size_t)(4 - t) * 32768; }
            else if (t <= 8) { j.xA = xc1 + (size_t)(t - 5) * 32768; j.xB = xc2 + (size_t)(8 - t) * 32768; }
            else             { const uint8_t* hp = hB(1, (t - 1) & 1); j.xA = hp; j.xB = hp + 32768; }
            j.hin = hB(0, (t - 1) & 1);
            j.cst = cst;
            j.hout = hB(0, t & 1);
            j.svA = nullptr; j.svB = nullptr; j.midp = nullptr; j.slot = 0;
        } else {
            const uint8_t* hx = hB(0, t & 1);
            j.xA = hx; j.xB = hx + 32768;
            j.hin = hB(1, (t - 1) & 1);
            j.cst = cst + 65536;
            j.hout = hB(1, t & 1);
            j.svA = (t >= 8) ? SA + (size_t)(t - 8) * 32768 : nullptr;
            j.svB = (t >= 8) ? SB + (size_t)(t - 8) * 32768 : nullptr;
            j.midp = (t >= 8 && t <= 11) ? midp : nullptr;
            j.slot = (t >= 8) ? (t - 8) : 0;
        }
        return j;
    };

    // t=1 layer0 alone
    k_cell<<<512, 512, 0, stream>>>(mkJob(1, 0), mkJob(1, 0));
    // t=2..8: layer0(t) || layer1(t-1)  (independent)
    for (int t = 2; t <= 8; ++t)
        k_cell<<<1024, 512, 0, stream>>>(mkJob(t, 0), mkJob(t - 1, 1));
    // layer1(8) alone
    k_cell<<<512, 512, 0, stream>>>(mkJob(8, 1), mkJob(8, 1));
    // AR steps: strictly serial
    for (int t = 9; t <= 15; ++t) {
        k_cell<<<512, 512, 0, stream>>>(mkJob(t, 0), mkJob(t, 0));
        k_cell<<<512, 512, 0, stream>>>(mkJob(t, 1), mkJob(t, 1));
    }

    k_outs<<<256, 512, 0, stream>>>(SA, SB, out);
    k_conv2<<<512, 256, 0, stream>>>(Wcp, midp, conv_b, out);
}